// Round 1
// baseline (399.821 us; speedup 1.0000x reference)
//
#include <hip/hip_runtime.h>
#include <math.h>

#define EPS 1e-5f

__device__ __forceinline__ float wave_sum64(float v) {
#pragma unroll
  for (int off = 32; off >= 1; off >>= 1) v += __shfl_xor(v, off, 64);
  return v;
}

// K1: x = weather @ W_emb + b_emb + pos_encoding
__global__ __launch_bounds__(64) void k_embed(
    const float* __restrict__ weather, const float* __restrict__ coords,
    const float* __restrict__ W_emb, const float* __restrict__ b_emb,
    float* __restrict__ x) {
  int row = blockIdx.x;  // b*1024 + s
  int e = threadIdx.x;
  int b = row >> 10, s = row & 1023;
  __shared__ float wrow[32];
  if (e < 31) wrow[e] = weather[row * 31 + e];
  __syncthreads();
  float acc = b_emb[e];
#pragma unroll
  for (int i = 0; i < 31; ++i) acc = fmaf(wrow[i], W_emb[i * 64 + e], acc);
  int g = e >> 2, rem = e & 3;
  // div = exp(4g * (-ln(10000)/64))
  float div = __expf(-0.5756462732485115f * (float)g);
  float pe;
  if (rem == 0)      pe = sinf((float)s * div);
  else if (rem == 1) pe = cosf((float)s * div);
  else if (rem == 2) pe = sinf(coords[b * 2 + 0] * 0.017453292519943295f * div);
  else               pe = cosf(coords[b * 2 + 1] * 0.017453292519943295f * div);
  x[row * 64 + e] = acc + pe;
}

// K2: qkv = x @ W_qkv + b_qkv; add gran embedding to q and k parts.
// Quirk (derived from torch reshape): q/k[b,s,e] += gran[temporal_index[s%8,1]][e]
__global__ __launch_bounds__(192) void k_qkv(
    const float* __restrict__ x, const float* __restrict__ Wq,
    const float* __restrict__ bq, const float* __restrict__ gran,
    const int* __restrict__ tidx, float* __restrict__ qkv) {
  int row = blockIdx.x, t = threadIdx.x;
  __shared__ float xrow[64];
  if (t < 64) xrow[t] = x[row * 64 + t];
  __syncthreads();
  float acc = bq[t];
#pragma unroll
  for (int i = 0; i < 64; ++i) acc = fmaf(xrow[i], Wq[i * 192 + t], acc);
  if (t < 128) {
    int tg = tidx[(row & 7) * 2 + 1];  // s%8 == row%8
    acc += gran[tg * 64 + (t & 63)];
  }
  qkv[row * 192 + t] = acc;
}

// K3: flash attention over the scrambled layout.
// bh = 8*(s%8)+h ; s2 = b*128 + s/8 ; hd = e%8.  64 bh slots, each attends
// over s2 in [0,1024) (mixes batches — faithful to reference quirk).
// Block = (bh, chunk of 256 queries). K/V rows for this bh staged in LDS.
__global__ __launch_bounds__(256) void k_attn(
    const float* __restrict__ qkv, float* __restrict__ ao) {
  int bh = blockIdx.x >> 2, chunk = blockIdx.x & 3;
  int slo = bh >> 3, h = bh & 7;
  __shared__ float4 kv[1024][4];  // [r][0..1]=K row, [2..3]=V row (64 KB)
  for (int r = threadIdx.x; r < 1024; r += 256) {
    int b = r >> 7, shi = r & 127;
    const float* base = qkv + (((b << 10) | (shi << 3) | slo) * 192) + (h << 3);
    kv[r][0] = *(const float4*)(base + 64);
    kv[r][1] = *(const float4*)(base + 68);
    kv[r][2] = *(const float4*)(base + 128);
    kv[r][3] = *(const float4*)(base + 132);
  }
  __syncthreads();

  int j = (chunk << 8) | threadIdx.x;          // query s2
  int bq = j >> 7, sq = ((j & 127) << 3) | slo;
  const float* qb = qkv + (((bq << 10) | sq) * 192) + (h << 3);
  float4 q0 = *(const float4*)qb;
  float4 q1 = *(const float4*)(qb + 4);
  const float scl = 0.35355339059327373f;  // 8^-0.5 folded into q
  q0.x *= scl; q0.y *= scl; q0.z *= scl; q0.w *= scl;
  q1.x *= scl; q1.y *= scl; q1.z *= scl; q1.w *= scl;

  float m = -1e30f, lsum = 0.f;
  float a[8];
#pragma unroll
  for (int i = 0; i < 8; ++i) a[i] = 0.f;

  for (int r = 0; r < 1024; r += 4) {
    float4 ka0 = kv[r + 0][0], kb0 = kv[r + 0][1];
    float4 ka1 = kv[r + 1][0], kb1 = kv[r + 1][1];
    float4 ka2 = kv[r + 2][0], kb2 = kv[r + 2][1];
    float4 ka3 = kv[r + 3][0], kb3 = kv[r + 3][1];
    float s0 = q0.x*ka0.x + q0.y*ka0.y + q0.z*ka0.z + q0.w*ka0.w
             + q1.x*kb0.x + q1.y*kb0.y + q1.z*kb0.z + q1.w*kb0.w;
    float s1 = q0.x*ka1.x + q0.y*ka1.y + q0.z*ka1.z + q0.w*ka1.w
             + q1.x*kb1.x + q1.y*kb1.y + q1.z*kb1.z + q1.w*kb1.w;
    float s2 = q0.x*ka2.x + q0.y*ka2.y + q0.z*ka2.z + q0.w*ka2.w
             + q1.x*kb2.x + q1.y*kb2.y + q1.z*kb2.z + q1.w*kb2.w;
    float s3 = q0.x*ka3.x + q0.y*ka3.y + q0.z*ka3.z + q0.w*ka3.w
             + q1.x*kb3.x + q1.y*kb3.y + q1.z*kb3.z + q1.w*kb3.w;
    float mx = fmaxf(fmaxf(s0, s1), fmaxf(s2, s3));
    float nm = fmaxf(m, mx);
    float esc = __expf(m - nm);  // == 0 when m == -1e30 (first tile)
    float p0 = __expf(s0 - nm), p1 = __expf(s1 - nm);
    float p2 = __expf(s2 - nm), p3 = __expf(s3 - nm);
    lsum = lsum * esc + (p0 + p1) + (p2 + p3);
    float4 va0 = kv[r + 0][2], vb0 = kv[r + 0][3];
    float4 va1 = kv[r + 1][2], vb1 = kv[r + 1][3];
    float4 va2 = kv[r + 2][2], vb2 = kv[r + 2][3];
    float4 va3 = kv[r + 3][2], vb3 = kv[r + 3][3];
    a[0] = fmaf(p3, va3.x, fmaf(p2, va2.x, fmaf(p1, va1.x, fmaf(p0, va0.x, a[0] * esc))));
    a[1] = fmaf(p3, va3.y, fmaf(p2, va2.y, fmaf(p1, va1.y, fmaf(p0, va0.y, a[1] * esc))));
    a[2] = fmaf(p3, va3.z, fmaf(p2, va2.z, fmaf(p1, va1.z, fmaf(p0, va0.z, a[2] * esc))));
    a[3] = fmaf(p3, va3.w, fmaf(p2, va2.w, fmaf(p1, va1.w, fmaf(p0, va0.w, a[3] * esc))));
    a[4] = fmaf(p3, vb3.x, fmaf(p2, vb2.x, fmaf(p1, vb1.x, fmaf(p0, vb0.x, a[4] * esc))));
    a[5] = fmaf(p3, vb3.y, fmaf(p2, vb2.y, fmaf(p1, vb1.y, fmaf(p0, vb0.y, a[5] * esc))));
    a[6] = fmaf(p3, vb3.z, fmaf(p2, vb2.z, fmaf(p1, vb1.z, fmaf(p0, vb0.z, a[6] * esc))));
    a[7] = fmaf(p3, vb3.w, fmaf(p2, vb2.w, fmaf(p1, vb1.w, fmaf(p0, vb0.w, a[7] * esc))));
    m = nm;
  }
  float inv = 1.0f / lsum;
  // inverse scramble == natural [b,s,e] layout
  float* o = ao + (((bq << 10) | sq) << 6) + (h << 3);
  *(float4*)(o + 0) = make_float4(a[0] * inv, a[1] * inv, a[2] * inv, a[3] * inv);
  *(float4*)(o + 4) = make_float4(a[4] * inv, a[5] * inv, a[6] * inv, a[7] * inv);
}

// K4: x1 = LayerNorm(x + ao @ W_out + b_out)  (one wave per row)
__global__ __launch_bounds__(64) void k_proj_ln(
    const float* __restrict__ x, const float* __restrict__ ao,
    const float* __restrict__ Wo, const float* __restrict__ bo,
    const float* __restrict__ g1, const float* __restrict__ be1,
    float* __restrict__ x1) {
  int row = blockIdx.x, e = threadIdx.x;
  __shared__ float arow[64];
  arow[e] = ao[row * 64 + e];
  __syncthreads();
  float acc = bo[e];
#pragma unroll
  for (int i = 0; i < 64; ++i) acc = fmaf(arow[i], Wo[i * 64 + e], acc);
  float y = x[row * 64 + e] + acc;
  float s1 = wave_sum64(y);
  float s2 = wave_sum64(y * y);
  float mean = s1 * 0.015625f;
  float var = s2 * 0.015625f - mean * mean;
  x1[row * 64 + e] = (y - mean) * rsqrtf(var + EPS) * g1[e] + be1[e];
}

// K5: x = LayerNorm(x1 + relu(x1 @ W1 + b1) @ W2 + b2)  (h1 stays in LDS)
__global__ __launch_bounds__(256) void k_ffn_ln(
    const float* __restrict__ x1, const float* __restrict__ W1,
    const float* __restrict__ b1, const float* __restrict__ W2,
    const float* __restrict__ b2, const float* __restrict__ g2,
    const float* __restrict__ be2, float* __restrict__ x) {
  int row = blockIdx.x, t = threadIdx.x;
  __shared__ float xrow[64];
  __shared__ float h1[256];
  __shared__ float part[4][64];
  if (t < 64) xrow[t] = x1[row * 64 + t];
  __syncthreads();
  float acc = b1[t];
#pragma unroll
  for (int i = 0; i < 64; ++i) acc = fmaf(xrow[i], W1[i * 256 + t], acc);
  h1[t] = fmaxf(acc, 0.f);
  __syncthreads();
  int e = t & 63, p = t >> 6;
  float a2 = 0.f;
  const float* w2p = W2 + (p << 6) * 64 + e;
  const float* hp = h1 + (p << 6);
#pragma unroll
  for (int i = 0; i < 64; ++i) a2 = fmaf(hp[i], w2p[i * 64], a2);
  part[p][e] = a2;
  __syncthreads();
  if (t < 64) {
    float y = part[0][t] + part[1][t] + part[2][t] + part[3][t] + b2[t] + xrow[t];
    float s1 = wave_sum64(y);
    float s2 = wave_sum64(y * y);
    float mean = s1 * 0.015625f;
    float var = s2 * 0.015625f - mean * mean;
    x[row * 64 + t] = (y - mean) * rsqrtf(var + EPS) * g2[t] + be2[t];
  }
}

// K6: out = x @ W_fc + b_fc   ([8192,64]x[64,31])
__global__ __launch_bounds__(256) void k_head(
    const float* __restrict__ x, const float* __restrict__ Wfc,
    const float* __restrict__ bfc, float* __restrict__ out) {
  int gid = blockIdx.x * 256 + threadIdx.x;
  int r = gid >> 5, o = gid & 31;
  if (o >= 31) return;
  float acc = bfc[o];
  const float* xr = x + r * 64;
#pragma unroll
  for (int i = 0; i < 64; ++i) acc = fmaf(xr[i], Wfc[i * 31 + o], acc);
  out[r * 31 + o] = acc;
}

extern "C" void kernel_launch(void* const* d_in, const int* in_sizes, int n_in,
                              void* d_out, int out_size, void* d_ws, size_t ws_size,
                              hipStream_t stream) {
  const float* weather = (const float*)d_in[0];
  const float* coords  = (const float*)d_in[1];
  const int*   tidx    = (const int*)d_in[2];
  const float* W_emb   = (const float*)d_in[3];
  const float* b_emb   = (const float*)d_in[4];
  const float* W_qkv   = (const float*)d_in[5];
  const float* b_qkv   = (const float*)d_in[6];
  const float* W_out   = (const float*)d_in[7];
  const float* b_out   = (const float*)d_in[8];
  const float* gran    = (const float*)d_in[9];
  const float* g1      = (const float*)d_in[10];
  const float* be1     = (const float*)d_in[11];
  const float* W1      = (const float*)d_in[12];
  const float* b1      = (const float*)d_in[13];
  const float* W2      = (const float*)d_in[14];
  const float* b2      = (const float*)d_in[15];
  const float* g2      = (const float*)d_in[16];
  const float* be2     = (const float*)d_in[17];
  const float* W_fc    = (const float*)d_in[18];
  const float* b_fc    = (const float*)d_in[19];
  float* out = (float*)d_out;

  // workspace layout (floats): x | x1 | qkv | ao  = 12.6 MB total
  float* x   = (float*)d_ws;
  float* x1  = x + 8192 * 64;
  float* qkv = x1 + 8192 * 64;
  float* ao  = qkv + 8192 * 192;

  k_embed<<<8192, 64, 0, stream>>>(weather, coords, W_emb, b_emb, x);
  for (int l = 0; l < 3; ++l) {
    k_qkv<<<8192, 192, 0, stream>>>(x, W_qkv + l * 64 * 192, b_qkv + l * 192,
                                    gran + l * 31 * 64, tidx, qkv);
    k_attn<<<256, 256, 0, stream>>>(qkv, ao);
    k_proj_ln<<<8192, 64, 0, stream>>>(x, ao, W_out + l * 64 * 64, b_out + l * 64,
                                       g1 + l * 64, be1 + l * 64, x1);
    k_ffn_ln<<<8192, 256, 0, stream>>>(x1, W1 + l * 64 * 256, b1 + l * 256,
                                       W2 + l * 256 * 64, b2 + l * 64,
                                       g2 + l * 64, be2 + l * 64, x);
  }
  k_head<<<1024, 256, 0, stream>>>(x, W_fc, b_fc, out);
}